// Round 12
// baseline (625.230 us; speedup 1.0000x reference)
//
#include <hip/hip_runtime.h>
#include <hip/hip_cooperative_groups.h>

namespace cg = cooperative_groups;

#define N_NODES 20000
#define HID     256
#define DEG     32
#define TOPK    16
#define NRB     313      // ceil(20000/64) row-blocks of 64
#define GRID_BLKS 768    // 3 blocks/CU guaranteed resident (LDS 27.6KB, lb(256,3))
#define PADE    8

typedef __attribute__((ext_vector_type(8))) short short8;
typedef __attribute__((ext_vector_type(4))) float f32x4;
typedef __attribute__((ext_vector_type(2))) _Float16 half2_t;

__device__ inline unsigned short f2bf(float f) {
    unsigned u = __float_as_uint(f);
    unsigned r = (u + 0x7FFFu + ((u >> 16) & 1u)) >> 16;  // RNE
    return (unsigned short)r;
}
__device__ inline float bf_lo(unsigned u) { return __uint_as_float(u << 16); }
__device__ inline float bf_hi(unsigned u) { return __uint_as_float(u & 0xFFFF0000u); }

__device__ inline unsigned short f2h(float f) {
    _Float16 h = (_Float16)f;
    return __builtin_bit_cast(unsigned short, h);
}
__device__ inline half2_t u2h2(unsigned u) { return __builtin_bit_cast(half2_t, u); }

__device__ inline ushort4 cvt4(float4 f) {
    ushort4 o;
    o.x = f2bf(f.x); o.y = f2bf(f.y); o.z = f2bf(f.z); o.w = f2bf(f.w);
    return o;
}

// Shared LDS for both GEMM phases (hoisted so the fused kernel allocates ONE copy)
struct GemmLds {
    unsigned short As[64][64 + PADE];
    unsigned short Ws[128][64 + PADE];
};

// ---------------------------------------------------------------------------
// GEMM accumulate core: 64x128 tile, BK=64, 256 thr (4 waves), mfma 16x16x32.
// OPERAND-SWAPPED mfma(W-frag, A-frag): D col = node, D regs = 4 consecutive
// output cols. A fp32 (AF32=1) or bf16; W fp32 (WF32=1, cvt in staging) or bf16.
// ---------------------------------------------------------------------------
template<int AF32, int WF32>
__device__ __forceinline__ void gemm_tile64(
    GemmLds& lds, const void* __restrict__ Araw, const void* __restrict__ Wraw,
    int M, int rowbase, int colbase, f32x4 acc[2][4])
{
    const int t    = threadIdx.x;
    const int lane = t & 63;
    const int wave = t >> 6;
    const int wm   = (wave & 1) * 32;
    const int wn   = (wave >> 1) * 64;

    const int lm = lane & 15;
    const int q8 = (lane >> 4) * 8;

    for (int k0 = 0; k0 < 256; k0 += 64) {
        #pragma unroll
        for (int c = 0; c < 2; ++c) {
            int idx = t + 256 * c;
            int row = idx >> 3;
            int col = (idx & 7) * 8;
            int grow = rowbase + row;
            if (AF32) {
                const float* A = (const float*)Araw;
                float4 f0 = make_float4(0.f, 0.f, 0.f, 0.f);
                float4 f1 = make_float4(0.f, 0.f, 0.f, 0.f);
                if (grow < M) {
                    f0 = *(const float4*)(A + (size_t)grow * 256 + k0 + col);
                    f1 = *(const float4*)(A + (size_t)grow * 256 + k0 + col + 4);
                }
                *(ushort4*)&lds.As[row][col]     = cvt4(f0);
                *(ushort4*)&lds.As[row][col + 4] = cvt4(f1);
            } else {
                const unsigned short* A = (const unsigned short*)Araw;
                uint4 av = make_uint4(0u, 0u, 0u, 0u);
                if (grow < M) av = *(const uint4*)(A + (size_t)grow * 256 + k0 + col);
                *(uint4*)&lds.As[row][col] = av;
            }
        }
        #pragma unroll
        for (int c = 0; c < 4; ++c) {
            int idx = t + 256 * c;
            int row = idx >> 3;
            int col = (idx & 7) * 8;
            if (WF32) {
                const float* W = (const float*)Wraw;
                float4 w0 = *(const float4*)(W + (size_t)(colbase + row) * 256 + k0 + col);
                float4 w1 = *(const float4*)(W + (size_t)(colbase + row) * 256 + k0 + col + 4);
                *(ushort4*)&lds.Ws[row][col]     = cvt4(w0);
                *(ushort4*)&lds.Ws[row][col + 4] = cvt4(w1);
            } else {
                const unsigned short* W = (const unsigned short*)Wraw;
                uint4 wv = *(const uint4*)(W + (size_t)(colbase + row) * 256 + k0 + col);
                *(uint4*)&lds.Ws[row][col] = wv;
            }
        }
        __syncthreads();

        #pragma unroll
        for (int kk = 0; kk < 64; kk += 32) {
            short8 af[2], bfr[4];
            #pragma unroll
            for (int i = 0; i < 2; ++i)
                af[i] = *(const short8*)&lds.As[wm + i * 16 + lm][kk + q8];
            #pragma unroll
            for (int j = 0; j < 4; ++j)
                bfr[j] = *(const short8*)&lds.Ws[wn + j * 16 + lm][kk + q8];
            #pragma unroll
            for (int i = 0; i < 2; ++i)
                #pragma unroll
                for (int j = 0; j < 4; ++j)
                    acc[i][j] = __builtin_amdgcn_mfma_f32_16x16x32_bf16(
                        bfr[j], af[i], acc[i][j], 0, 0, 0);   // swapped operands
        }
        __syncthreads();
    }
}

// ---------------------------------------------------------------------------
// Phase 1 unit: u<1920 GEMM(q/k/v), 1920..1983 Wo cvt, 1984..4483 topk.
// ---------------------------------------------------------------------------
__device__ __forceinline__ void qkv_unit(
    int u, GemmLds& lds,
    const float* __restrict__ A,
    const float* __restrict__ Wq, const float* __restrict__ Wk,
    const float* __restrict__ Wv, const float* __restrict__ Wo,
    const float* __restrict__ bq, const float* __restrict__ bk,
    const float* __restrict__ bv,
    const float* __restrict__ ew,
    unsigned short* __restrict__ Cq, unsigned short* __restrict__ kv,
    unsigned short* __restrict__ Wob, float* __restrict__ wgt, int M)
{
    const int t = threadIdx.x;

    if (u >= 1984) {                      // ---- topk ----
        int n = (u - 1984) * 8 + (t >> 5);
        int lane = t & 31;
        float my = ew[n * 32 + lane];
        int cnt = 0;
        #pragma unroll
        for (int j = 0; j < 32; ++j) {
            float o = __shfl(my, j, 32);
            cnt += (o > my || (o == my && j < lane)) ? 1 : 0;
        }
        float w = (cnt < TOPK) ? my : 0.0f;
        float s = w;
        #pragma unroll
        for (int off = 16; off; off >>= 1) s += __shfl_xor(s, off, 32);
        wgt[n * 32 + lane] = w / (s + 1e-5f);
        return;
    }
    if (u >= 1920) {                      // ---- Wo convert ----
        int i = (u - 1920) * 256 + t;     // 16384 float4
        ((ushort4*)Wob)[i] = cvt4(((const float4*)Wo)[i]);
        return;
    }

    const int xcd     = u & 7;
    const int rest    = u >> 3;
    const int rowblk  = xcd + 8 * (rest / 6);
    const int variant = rest % 6;
    if (rowblk >= NRB) return;            // whole block uniform -> safe
    const int z  = variant >> 1;
    const int by = variant & 1;

    const float* W    = (z == 0) ? Wq : (z == 1) ? Wk : Wv;
    const float* bias = (z == 0) ? bq : (z == 1) ? bk : bv;

    f32x4 acc[2][4];
    #pragma unroll
    for (int i = 0; i < 2; ++i)
        #pragma unroll
        for (int j = 0; j < 4; ++j)
            acc[i][j] = (f32x4){0.f, 0.f, 0.f, 0.f};

    gemm_tile64<1, 1>(lds, A, W, M, rowblk * 64, by * 128, acc);

    const int lane = t & 63;
    const int wave = t >> 6;
    const int wm   = (wave & 1) * 32;
    const int wn   = (wave >> 1) * 64;
    const int lm   = lane & 15;
    const int lq   = lane >> 4;

    #pragma unroll
    for (int i = 0; i < 2; ++i) {
        int node = rowblk * 64 + wm + i * 16 + lm;
        if (node >= M) continue;
        #pragma unroll
        for (int j = 0; j < 4; ++j) {
            int col0 = by * 128 + wn + j * 16 + lq * 4;
            float4 b4 = *(const float4*)(bias + col0);
            float x0 = acc[i][j][0] + b4.x;
            float x1 = acc[i][j][1] + b4.y;
            float x2 = acc[i][j][2] + b4.z;
            float x3 = acc[i][j][3] + b4.w;
            int hh = col0 >> 5, cc = col0 & 31;
            if (z == 0) {
                ushort4 o; o.x = f2h(x0); o.y = f2h(x1); o.z = f2h(x2); o.w = f2h(x3);
                *(ushort4*)(Cq + (size_t)hh * ((size_t)N_NODES * 32)
                               + (size_t)node * 32 + cc) = o;
            } else if (z == 1) {
                ushort4 o; o.x = f2h(x0); o.y = f2h(x1); o.z = f2h(x2); o.w = f2h(x3);
                *(ushort4*)(kv + (size_t)hh * ((size_t)N_NODES * 64)
                               + (size_t)node * 64 + (cc >> 2) * 8) = o;
            } else {
                ushort4 o; o.x = f2bf(x0); o.y = f2bf(x1); o.z = f2bf(x2); o.w = f2bf(x3);
                *(ushort4*)(kv + (size_t)hh * ((size_t)N_NODES * 64)
                               + (size_t)node * 64 + (cc >> 2) * 8 + 4) = o;
            }
        }
    }
}

// ---------------------------------------------------------------------------
// Phase 2 unit: attention for 8 nodes of head u&7 (XCD-pinned L2 shard).
// kv [8][N][64] in 16B chunks {4 k fp16 | 4 v bf16}; fully-coalesced gathers;
// reduce-scatter dot reduction; group-wide exp2 softmax.
// ---------------------------------------------------------------------------
__device__ __forceinline__ void attn_unit(
    int u,
    const unsigned short* __restrict__ qh, const unsigned short* __restrict__ kv,
    const int* __restrict__ nbr, const float* __restrict__ wgt,
    unsigned short* __restrict__ agg)
{
    const int h    = u & 7;
    const int t    = threadIdx.x;
    const int lane = t & 31;
    const int n    = (u >> 3) * 8 + (t >> 5);

    const size_t hkv = (size_t)h * ((size_t)N_NODES * 64);
    const size_t hq  = (size_t)h * ((size_t)N_NODES * 32);

    const int   nbv = nbr[n * 32 + lane];
    const float w   = wgt[n * 32 + lane];

    const int cg = lane & 7;
    const int dg = lane >> 3;

    int nbj[8];
    #pragma unroll
    for (int j = 0; j < 8; ++j)
        nbj[j] = __shfl(nbv, dg + 4 * j, 32);

    uint4 kvr[8];
    #pragma unroll
    for (int j = 0; j < 8; ++j)
        kvr[j] = *(const uint4*)(kv + hkv + (size_t)nbj[j] * 64 + cg * 8);

    uint2 qc = *(const uint2*)(qh + hq + (size_t)n * 32 + cg * 4);

    float p[8];
    #pragma unroll
    for (int j = 0; j < 8; ++j) {
        float s = __builtin_amdgcn_fdot2(u2h2(kvr[j].x), u2h2(qc.x), 0.f, false);
        p[j]    = __builtin_amdgcn_fdot2(u2h2(kvr[j].y), u2h2(qc.y), s, false);
    }

    // reduce-scatter over cg (xor 4,2,1): lane ends with full dot of nbr dg+4cg
    const bool b4 = (cg & 4) != 0;
    float q4[4];
    #pragma unroll
    for (int jj = 0; jj < 4; ++jj) {
        float snd = b4 ? p[jj] : p[jj + 4];
        float kp  = b4 ? p[jj + 4] : p[jj];
        q4[jj] = kp + __shfl_xor(snd, 4, 32);
    }
    const bool b2 = (cg & 2) != 0;
    float q2[2];
    #pragma unroll
    for (int jj = 0; jj < 2; ++jj) {
        float snd = b2 ? q4[jj] : q4[jj + 2];
        float kp  = b2 ? q4[jj + 2] : q4[jj];
        q2[jj] = kp + __shfl_xor(snd, 2, 32);
    }
    const bool b1 = (cg & 1) != 0;
    {
        float snd = b1 ? q2[0] : q2[1];
        float kp  = b1 ? q2[1] : q2[0];
        q2[0] = kp + __shfl_xor(snd, 1, 32);
    }
    const float sc = q2[0];
    const float wm = __shfl(w, dg + 4 * cg, 32);

    float z = sc * wm * 0.25500917211914f;          // / sqrt(32) * log2(e)
    float mx = z;
    #pragma unroll
    for (int off = 1; off <= 16; off <<= 1)
        mx = fmaxf(mx, __shfl_xor(mx, off, 32));
    float e = __builtin_amdgcn_exp2f(z - mx);
    float ssum = e;
    #pragma unroll
    for (int off = 1; off <= 16; off <<= 1)
        ssum += __shfl_xor(ssum, off, 32);
    const float aw = e * __builtin_amdgcn_rcpf(ssum);

    float a0 = 0.f, a1 = 0.f, a2 = 0.f, a3 = 0.f;
    #pragma unroll
    for (int j = 0; j < 8; ++j) {
        float awv = __shfl(aw, 8 * dg + j, 32);
        a0 = fmaf(awv, bf_lo(kvr[j].z), a0);
        a1 = fmaf(awv, bf_hi(kvr[j].z), a1);
        a2 = fmaf(awv, bf_lo(kvr[j].w), a2);
        a3 = fmaf(awv, bf_hi(kvr[j].w), a3);
    }
    a0 += __shfl_xor(a0, 8, 32);  a0 += __shfl_xor(a0, 16, 32);
    a1 += __shfl_xor(a1, 8, 32);  a1 += __shfl_xor(a1, 16, 32);
    a2 += __shfl_xor(a2, 8, 32);  a2 += __shfl_xor(a2, 16, 32);
    a3 += __shfl_xor(a3, 8, 32);  a3 += __shfl_xor(a3, 16, 32);

    if (dg == 0) {
        ushort4 o;
        o.x = f2bf(a0); o.y = f2bf(a1); o.z = f2bf(a2); o.w = f2bf(a3);
        *(ushort4*)(agg + (size_t)n * 256 + h * 32 + cg * 4) = o;
    }
}

// ---------------------------------------------------------------------------
// Phase 3 unit: o-projection (A=agg bf16, W=Wo bf16, fp32 out + leaky-relu).
// 640 units, XCD-pinned.
// ---------------------------------------------------------------------------
__device__ __forceinline__ void out_unit(
    int u, GemmLds& lds,
    const unsigned short* __restrict__ A, const unsigned short* __restrict__ W,
    const float* __restrict__ bias, float* __restrict__ out, int M)
{
    const int xcd    = u & 7;
    const int rest   = u >> 3;            // 0..79
    const int rowblk = xcd + 8 * (rest >> 1);
    const int ch     = rest & 1;
    if (rowblk >= NRB) return;

    f32x4 acc[2][4];
    #pragma unroll
    for (int i = 0; i < 2; ++i)
        #pragma unroll
        for (int j = 0; j < 4; ++j)
            acc[i][j] = (f32x4){0.f, 0.f, 0.f, 0.f};

    gemm_tile64<0, 0>(lds, A, W, M, rowblk * 64, ch * 128, acc);

    const int lane = threadIdx.x & 63;
    const int wave = threadIdx.x >> 6;
    const int wm   = (wave & 1) * 32;
    const int wn   = (wave >> 1) * 64;
    const int lm   = lane & 15;
    const int lq   = lane >> 4;

    #pragma unroll
    for (int i = 0; i < 2; ++i) {
        int node = rowblk * 64 + wm + i * 16 + lm;
        if (node >= M) continue;
        #pragma unroll
        for (int j = 0; j < 4; ++j) {
            int col0 = ch * 128 + wn + j * 16 + lq * 4;
            float4 b4 = *(const float4*)(bias + col0);
            float4 o;
            o.x = acc[i][j][0] + b4.x;
            o.y = acc[i][j][1] + b4.y;
            o.z = acc[i][j][2] + b4.z;
            o.w = acc[i][j][3] + b4.w;
            o.x = (o.x >= 0.f) ? o.x : 0.01f * o.x;
            o.y = (o.y >= 0.f) ? o.y : 0.01f * o.y;
            o.z = (o.z >= 0.f) ? o.z : 0.01f * o.z;
            o.w = (o.w >= 0.f) ? o.w : 0.01f * o.w;
            *(float4*)(out + (size_t)node * 256 + col0) = o;
        }
    }
}

// ---------------------------------------------------------------------------
// Fused cooperative kernel: phase1 -> grid.sync -> attn -> grid.sync -> out.
// 768 blocks (3/CU resident). 768 % 8 == 0 keeps unit&7 == blockIdx&7, so
// XCD pinning (GEMM row-blocks, attn head shards) survives the grid-stride.
// __threadfence() = agent-scope fence (L2 wb/inv) for cross-XCD visibility.
// ---------------------------------------------------------------------------
__global__ __launch_bounds__(256, 3) void fused_kernel(
    const float* __restrict__ h, const int* __restrict__ nbr,
    const float* __restrict__ ew,
    const float* __restrict__ Wq, const float* __restrict__ Wk,
    const float* __restrict__ Wv, const float* __restrict__ Wo,
    const float* __restrict__ bq, const float* __restrict__ bk,
    const float* __restrict__ bv, const float* __restrict__ bo,
    float* __restrict__ out,
    unsigned short* __restrict__ qb, unsigned short* __restrict__ kvb,
    unsigned short* __restrict__ aggb, unsigned short* __restrict__ Wob,
    float* __restrict__ wgt)
{
    __shared__ GemmLds lds;
    cg::grid_group grid = cg::this_grid();
    const int b = blockIdx.x;

    for (int u = b; u < 4484; u += GRID_BLKS)
        qkv_unit(u, lds, h, Wq, Wk, Wv, Wo, bq, bk, bv, ew,
                 qb, kvb, Wob, wgt, N_NODES);

    __threadfence();
    grid.sync();
    __threadfence();

    for (int u = b; u < 20000; u += GRID_BLKS)
        attn_unit(u, qb, kvb, nbr, wgt, aggb);

    __threadfence();
    grid.sync();
    __threadfence();

    for (int u = b; u < 640; u += GRID_BLKS)
        out_unit(u, lds, aggb, Wob, bo, out, N_NODES);
}

// ---------------------------------------------------------------------------
// Fallback (non-cooperative) wrappers — identical math, 3 dispatches.
// ---------------------------------------------------------------------------
__global__ __launch_bounds__(256) void k_qkv(
    const float* h, const float* Wq, const float* Wk, const float* Wv,
    const float* Wo, const float* bq, const float* bk, const float* bv,
    const float* ew, unsigned short* qb, unsigned short* kvb,
    unsigned short* Wob, float* wgt)
{
    __shared__ GemmLds lds;
    qkv_unit(blockIdx.x, lds, h, Wq, Wk, Wv, Wo, bq, bk, bv, ew,
             qb, kvb, Wob, wgt, N_NODES);
}
__global__ __launch_bounds__(256) void k_attn(
    const unsigned short* qb, const unsigned short* kvb, const int* nbr,
    const float* wgt, unsigned short* aggb)
{
    attn_unit(blockIdx.x, qb, kvb, nbr, wgt, aggb);
}
__global__ __launch_bounds__(256) void k_out(
    const unsigned short* aggb, const unsigned short* Wob, const float* bo,
    float* out)
{
    __shared__ GemmLds lds;
    out_unit(blockIdx.x, lds, aggb, Wob, bo, out, N_NODES);
}

// ---------------------------------------------------------------------------
extern "C" void kernel_launch(void* const* d_in, const int* in_sizes, int n_in,
                              void* d_out, int out_size, void* d_ws, size_t ws_size,
                              hipStream_t stream)
{
    const float* h   = (const float*)d_in[0];
    const int*   nbr = (const int*)  d_in[1];
    const float* ew  = (const float*)d_in[2];
    const float* Wq  = (const float*)d_in[3];
    const float* bq  = (const float*)d_in[4];
    const float* Wk  = (const float*)d_in[5];
    const float* bk  = (const float*)d_in[6];
    const float* Wv  = (const float*)d_in[7];
    const float* bv  = (const float*)d_in[8];
    const float* Wo  = (const float*)d_in[9];
    const float* bo  = (const float*)d_in[10];
    float* out = (float*)d_out;

    const size_t NM = (size_t)N_NODES * HID;   // 5,120,000
    char* ws = (char*)d_ws;
    unsigned short* qb   = (unsigned short*)ws; ws += NM * 2;   // fp16 [8][N][32]
    unsigned short* kvb  = (unsigned short*)ws; ws += NM * 4;   // [8][N][64] 16B-chunk k|v
    unsigned short* aggb = (unsigned short*)ws; ws += NM * 2;   // bf16 [N][256]
    unsigned short* Wob  = (unsigned short*)ws; ws += 65536 * 2;
    float* wgt = (float*)ws;                    ws += (size_t)N_NODES * 32 * 4;

    void* args[] = {
        (void*)&h, (void*)&nbr, (void*)&ew,
        (void*)&Wq, (void*)&Wk, (void*)&Wv, (void*)&Wo,
        (void*)&bq, (void*)&bk, (void*)&bv, (void*)&bo,
        (void*)&out,
        (void*)&qb, (void*)&kvb, (void*)&aggb, (void*)&Wob, (void*)&wgt
    };

    hipError_t err = hipLaunchCooperativeKernel(
        (const void*)fused_kernel, dim3(GRID_BLKS), dim3(256), args, 0, stream);

    if (err != hipSuccess) {
        // deterministic fallback: classic 3-dispatch path
        k_qkv<<<dim3(4484), dim3(256), 0, stream>>>(h, Wq, Wk, Wv, Wo,
                                                    bq, bk, bv, ew,
                                                    qb, kvb, Wob, wgt);
        k_attn<<<dim3(20000), dim3(256), 0, stream>>>(qb, kvb, nbr, wgt, aggb);
        k_out<<<dim3(640), dim3(256), 0, stream>>>(aggb, Wob, bo, out);
    }
}